// Round 8
// baseline (1614.384 us; speedup 1.0000x reference)
//
#include <hip/hip_runtime.h>
#include <cstdint>
#include <cstddef>

#define DEV __device__ __forceinline__

typedef __attribute__((ext_vector_type(4))) float    f32x4;
typedef __attribute__((ext_vector_type(4))) _Float16 f16x4;
typedef __attribute__((ext_vector_type(8))) _Float16 f16x8;

static constexpr int B_ = 128, T_ = 1024, F_ = 128, H_ = 128, L_ = 7;
static constexpr int M_ = B_ * T_;       // 131072
static constexpr int NCH = 128;          // 8-step chunks per sequence

// ---------- numeric helpers ----------
DEV float fexp2(float x){
#if __has_builtin(__builtin_amdgcn_exp2f)
  return __builtin_amdgcn_exp2f(x);
#else
  return exp2f(x);
#endif
}
DEV float frcp(float x){
#if __has_builtin(__builtin_amdgcn_rcpf)
  return __builtin_amdgcn_rcpf(x);
#else
  return 1.0f/x;
#endif
}
DEV float fsig(float x){ return frcp(1.f + fexp2(-1.44269504f*x)); }
// tanh(x) = 2*sigmoid(2x) - 1 ; exp2(+-inf) -> 0/inf, rcp(inf)=0 => saturates correctly
DEV float ftanh(float x){ return 2.f*frcp(1.f + fexp2(-2.88539008f*x)) - 1.f; }
DEV void  ntst4(_Float16* p, f16x4 v){ __builtin_nontemporal_store(v, (f16x4*)p); }

// ---------- converts ----------
__global__ void k_cvt_x(const float4* __restrict__ x4, f16x4* __restrict__ xo, int n4){
  int i = blockIdx.x*blockDim.x + threadIdx.x;
  int stride = gridDim.x*blockDim.x;
  for (; i < n4; i += stride){
    float4 v = x4[i];
    f16x4 o = {(_Float16)v.x, (_Float16)v.y, (_Float16)v.z, (_Float16)v.w};
    xo[i] = o;
  }
}

// Row order m2 = 64w + 16mt + 4q + r  <->  (gate=r, hrow=16w+4q+mt).
// Wc[l][m2][k] f16: k<128 -> Whh[l][r*128+hrow][k], k>=128 -> Wih[l][r*128+hrow][k-128].
// biasc[l][m2] f32 = bih+bhh (same m2 order; consumed as float4 at m2/4).
__global__ void k_cvt_w(const float* __restrict__ Wih, const float* __restrict__ Whh,
                        const float* __restrict__ bih, const float* __restrict__ bhh,
                        _Float16* __restrict__ Wc, float* __restrict__ biasc){
  int idx = blockIdx.x*blockDim.x + threadIdx.x;          // 3584*256 = 917504 exact
  int l    = idx >> 17;            // /(512*256)
  int rem  = idx & 131071;
  int m2   = rem >> 8;
  int k    = rem & 255;
  int w  = m2 >> 6;
  int mt = (m2 >> 4) & 3;
  int q  = (m2 >> 2) & 3;
  int r  = m2 & 3;
  int hrow = 16*w + 4*q + mt;
  int srow = l*512 + r*128 + hrow;
  float v = (k < 128) ? Whh[(size_t)srow*128 + k] : Wih[(size_t)srow*128 + (k-128)];
  Wc[idx] = (_Float16)v;
  if (idx < L_*512){
    int bl = idx >> 9, bm = idx & 511;
    int bw = bm >> 6, bmt = (bm >> 4) & 3, bq = (bm >> 2) & 3, br = bm & 3;
    int bs = bl*512 + br*128 + (16*bw + 4*bq + bmt);
    biasc[idx] = bih[bs] + bhh[bs];
  }
}

// ---------- fused wavefront recurrence (single kernel, 56 WGs) ----------
// wg = layer*8 + group; 512 thr (8 waves), 16 batches per WG.
// Split: z(t) = [bias + Wih*x(t)] (xz, computed 2 steps AHEAD, off critical path)
//             + Whh*h(t-1)        (16 MFMA k=128 on the critical path).
// m2 row order gives lane (w,q,i): acc[mt] = 4 gates of hrow 16w+4q+mt, batch i
// -> in-lane gate math, h-rows contiguous -> ONE ds_write_b64 per lane.
// x staged global->LDS ring xb[4] (plain coalesced loads, 3 rows ahead);
// h flushed with NT stores (MALL-coherent), relaxed flags + vmcnt(0) drain
// every 8 steps (R7-proven protocol). Per-step barrier waits lgkmcnt ONLY.
__global__ __launch_bounds__(512) void k_wave(
    const _Float16* __restrict__ xcvt,
    _Float16* __restrict__ buf0, _Float16* __restrict__ buf1,
    const _Float16* __restrict__ Wc, const float4* __restrict__ biasc,
    int* __restrict__ flags){
  const int wg = blockIdx.x;
  const int layer = wg >> 3;
  const int g = wg & 7;
  const int tid = threadIdx.x;
  const int w = tid >> 6, l64 = tid & 63;
  const int q = l64 >> 4, i = l64 & 15;

  const _Float16* src = (layer == 0) ? xcvt : (((layer - 1) & 1) ? buf1 : buf0);
  _Float16* dst = (layer & 1) ? buf1 : buf0;

  __shared__ _Float16 hx[2][16][132];   // h double buffer (bank-clean stride 132)
  __shared__ _Float16 xb[4][16][132];   // x ring, 4 rows

  // A-frags: wfH/wfX[mt][kt] row m2 = 64w+16mt+i, k = 32kt+8q (+128 for X)
  f16x8 wfH[4][4], wfX[4][4];
  {
    const _Float16* wbase = Wc + ((size_t)(layer*512) + 64*w + i)*256 + 8*q;
#pragma unroll
    for (int mt = 0; mt < 4; ++mt)
#pragma unroll
      for (int kt = 0; kt < 4; ++kt){
        wfH[mt][kt] = *(const f16x8*)(wbase + (size_t)(16*mt)*256 + 32*kt);
        wfX[mt][kt] = *(const f16x8*)(wbase + (size_t)(16*mt)*256 + 128 + 32*kt);
      }
  }
  f32x4 bias[4];
#pragma unroll
  for (int mt = 0; mt < 4; ++mt){
    float4 bv = biasc[layer*128 + 16*w + 4*mt + q];
    f32x4 t = {bv.x, bv.y, bv.z, bv.w};
    bias[mt] = t;
  }
  float cst[4] = {0.f, 0.f, 0.f, 0.f};

  const int bb = tid >> 5;          // batch 0..15 (staging/flush role)
  const int cc = tid & 31;          // 4-elem chunk 0..31
  const size_t srow = ((size_t)(g*16 + bb))*T_*H_;
  const _Float16* xsrc = src + srow + cc*4;
  _Float16*       hdst = dst + srow + cc*4;
  int* fIn  = flags + ((layer > 0 ? layer - 1 : 0)*8 + g)*NCH;
  int* fOut = flags + (layer*8 + g)*NCH;

  auto poll = [&](int* p){
    if (tid == 0){
      while (__hip_atomic_load(p, __ATOMIC_RELAXED, __HIP_MEMORY_SCOPE_AGENT) == 0)
        __builtin_amdgcn_s_sleep(2);
    }
    __syncthreads();
  };

  // ---- prologue: gate chunk 0, zero h, stage x rows 0..2, prefetch 3,4 ----
  if (layer > 0) poll(fIn + 0);
  {
    f16x4 z4 = {(_Float16)0.f, (_Float16)0.f, (_Float16)0.f, (_Float16)0.f};
    *(f16x4*)&hx[0][bb][cc*4] = z4;
    f16x4 r0 = *(const f16x4*)(xsrc);
    f16x4 r1 = *(const f16x4*)(xsrc + (size_t)H_);
    f16x4 r2 = *(const f16x4*)(xsrc + (size_t)2*H_);
    *(f16x4*)&xb[0][bb][cc*4] = r0;
    *(f16x4*)&xb[1][bb][cc*4] = r1;
    *(f16x4*)&xb[2][bb][cc*4] = r2;
  }
  f16x4 xn0 = *(const f16x4*)(xsrc + (size_t)3*H_);
  f16x4 xn1 = *(const f16x4*)(xsrc + (size_t)4*H_);
  __syncthreads();

  // prologue refills: xzA = bias + Wx*x(0), xzB = bias + Wx*x(1)
  f32x4 xzA[4], xzB[4];
  {
    f16x8 b0[4], b1[4];
#pragma unroll
    for (int kt = 0; kt < 4; ++kt){
      b0[kt] = *(const f16x8*)&xb[0][i][32*kt + 8*q];
      b1[kt] = *(const f16x8*)&xb[1][i][32*kt + 8*q];
    }
#pragma unroll
    for (int mt = 0; mt < 4; ++mt){
      xzA[mt] = bias[mt]; xzB[mt] = bias[mt];
#pragma unroll
      for (int kt = 0; kt < 4; ++kt){
        xzA[mt] = __builtin_amdgcn_mfma_f32_16x16x32_f16(wfX[mt][kt], b0[kt], xzA[mt], 0, 0, 0);
        xzB[mt] = __builtin_amdgcn_mfma_f32_16x16x32_f16(wfX[mt][kt], b1[kt], xzB[mt], 0, 0, 0);
      }
    }
  }

#define BODY(XZ, CUR, TT)                                                        \
  {                                                                              \
    f16x4 freg;                                                                  \
    if ((TT) > 0) freg = *(const f16x4*)&hx[CUR][bb][cc*4];                      \
    f16x8 bf[4], bx[4];                                                          \
    _Pragma("unroll")                                                            \
    for (int kt = 0; kt < 4; ++kt)                                               \
      bf[kt] = *(const f16x8*)&hx[CUR][i][32*kt + 8*q];                          \
    {                                                                            \
      const _Float16* xrow = &xb[((TT) + 2) & 3][i][8*q];                        \
      _Pragma("unroll")                                                          \
      for (int kt = 0; kt < 4; ++kt)                                             \
        bx[kt] = *(const f16x8*)(xrow + 32*kt);                                  \
    }                                                                            \
    f32x4 acc[4];                                                                \
    _Pragma("unroll")                                                            \
    for (int mt = 0; mt < 4; ++mt) acc[mt] = XZ[mt];                             \
    _Pragma("unroll")                                                            \
    for (int kt = 0; kt < 4; ++kt){                                              \
      acc[0] = __builtin_amdgcn_mfma_f32_16x16x32_f16(wfH[0][kt], bf[kt], acc[0], 0, 0, 0); \
      acc[1] = __builtin_amdgcn_mfma_f32_16x16x32_f16(wfH[1][kt], bf[kt], acc[1], 0, 0, 0); \
      acc[2] = __builtin_amdgcn_mfma_f32_16x16x32_f16(wfH[2][kt], bf[kt], acc[2], 0, 0, 0); \
      acc[3] = __builtin_amdgcn_mfma_f32_16x16x32_f16(wfH[3][kt], bf[kt], acc[3], 0, 0, 0); \
    }                                                                            \
    if ((TT) > 0) ntst4(hdst + (size_t)((TT) - 1)*H_, freg);                     \
    *(f16x4*)&xb[((TT) + 3) & 3][bb][cc*4] = xn0;                                \
    xn0 = xn1;                                                                   \
    { int rp = (TT) + 5; if (rp > T_ - 1) rp = T_ - 1;                           \
      xn1 = *(const f16x4*)(xsrc + (size_t)rp*H_); }                             \
    f16x4 hv;                                                                    \
    _Pragma("unroll")                                                            \
    for (int mt = 0; mt < 4; ++mt){                                              \
      f32x4 z = acc[mt];                                                         \
      float si = fsig(z[0]), sf = fsig(z[1]);                                    \
      float gt = ftanh(z[2]);                                                    \
      float so = fsig(z[3]);                                                     \
      cst[mt] = sf*cst[mt] + si*gt;                                              \
      hv[mt] = (_Float16)(so * ftanh(cst[mt]));                                  \
    }                                                                            \
    *(f16x4*)&hx[(CUR) ^ 1][i][16*w + 4*q] = hv;                                 \
    _Pragma("unroll")                                                            \
    for (int mt = 0; mt < 4; ++mt) XZ[mt] = bias[mt];                            \
    _Pragma("unroll")                                                            \
    for (int kt = 0; kt < 4; ++kt){                                              \
      XZ[0] = __builtin_amdgcn_mfma_f32_16x16x32_f16(wfX[0][kt], bx[kt], XZ[0], 0, 0, 0); \
      XZ[1] = __builtin_amdgcn_mfma_f32_16x16x32_f16(wfX[1][kt], bx[kt], XZ[1], 0, 0, 0); \
      XZ[2] = __builtin_amdgcn_mfma_f32_16x16x32_f16(wfX[2][kt], bx[kt], XZ[2], 0, 0, 0); \
      XZ[3] = __builtin_amdgcn_mfma_f32_16x16x32_f16(wfX[3][kt], bx[kt], XZ[3], 0, 0, 0); \
    }                                                                            \
    asm volatile("s_waitcnt lgkmcnt(0)\n\ts_barrier" ::: "memory");              \
  }

  for (int t = 0; t < T_; t += 2){
    BODY(xzA, 0, t)
    // chunk boundary: after completing step t (t%8==0, t>0) rows <= t-1 flushed
    if (layer < 6 && t > 0 && (t & 7) == 0){
      asm volatile("s_waitcnt vmcnt(0)" ::: "memory");
      __syncthreads();
      if (tid == 0)
        __hip_atomic_store(fOut + ((t >> 3) - 1), 1, __ATOMIC_RELAXED, __HIP_MEMORY_SCOPE_AGENT);
    }
    // gate the odd body's load of row (t+1)+5
    if (layer > 0 && ((t + 6) & 7) == 0 && (t + 6) < T_) poll(fIn + ((t + 6) >> 3));
    BODY(xzB, 1, t + 1)
  }
#undef BODY

  // final flush: h(1023) lives in hx[0]
  {
    f16x4 freg = *(const f16x4*)&hx[0][bb][cc*4];
    ntst4(hdst + (size_t)(T_ - 1)*H_, freg);
  }
  if (layer < 6){
    asm volatile("s_waitcnt vmcnt(0)" ::: "memory");
    __syncthreads();
    if (tid == 0)
      __hip_atomic_store(fOut + (NCH - 1), 1, __ATOMIC_RELAXED, __HIP_MEMORY_SCOPE_AGENT);
  }
}

// ---------- attention (only head A-1 matters) + final linear + sigmoid ----------
__global__ __launch_bounds__(256) void k_attn(const _Float16* __restrict__ out,
                                              const float* __restrict__ Wa, const float* __restrict__ ba,
                                              const float* __restrict__ Wf, const float* __restrict__ bfv,
                                              float* __restrict__ y){
  int b = blockIdx.x, tid = threadIdx.x;
  __shared__ float was[H_];
  __shared__ float p[T_];
  __shared__ float red[64];
  __shared__ float app[256];
  if (tid < H_) was[tid] = Wa[127*H_ + tid];
  __syncthreads();
  float bav = ba[127];
  for (int t = tid; t < T_; t += 256){
    const _Float16* row = out + (size_t)(b*T_ + t)*H_;
    float acc = 0.f;
#pragma unroll
    for (int k = 0; k < H_; k += 8){
      f16x8 u = *(const f16x8*)(row + k);
      acc += (float)u[0]*was[k+0] + (float)u[1]*was[k+1]
           + (float)u[2]*was[k+2] + (float)u[3]*was[k+3]
           + (float)u[4]*was[k+4] + (float)u[5]*was[k+5]
           + (float)u[6]*was[k+6] + (float)u[7]*was[k+7];
    }
    p[t] = ftanh(acc + bav);
  }
  __syncthreads();
  float m = -1e30f;
  for (int t = tid; t < T_; t += 256) m = fmaxf(m, p[t]);
  for (int off = 32; off; off >>= 1) m = fmaxf(m, __shfl_xor(m, off));
  if ((tid & 63) == 0) red[tid >> 6] = m;
  __syncthreads();
  if (tid == 0) red[8] = fmaxf(fmaxf(red[0], red[1]), fmaxf(red[2], red[3]));
  __syncthreads();
  float smax = red[8];
  float lsum = 0.f;
  for (int t = tid; t < T_; t += 256){
    float e = fexp2(1.44269504f*(p[t] - smax));
    p[t] = e; lsum += e;
  }
  for (int off = 32; off; off >>= 1) lsum += __shfl_xor(lsum, off);
  if ((tid & 63) == 0) red[16 + (tid >> 6)] = lsum;
  __syncthreads();
  float rden = frcp(red[16] + red[17] + red[18] + red[19]);
  int h = tid & (H_ - 1);
  int half = tid >> 7;
  float acc = 0.f;
  for (int t = half*512; t < half*512 + 512; ++t)
    acc += p[t] * (float)out[(size_t)(b*T_ + t)*H_ + h];
  app[tid] = acc;
  __syncthreads();
  if (tid < H_){
    float applied = (app[tid] + app[tid + H_]) * rden;
    float v = applied * Wf[tid];
    for (int off = 32; off; off >>= 1) v += __shfl_xor(v, off);
    if (tid == 0)  red[32] = v;
    if (tid == 64) red[33] = v;
  }
  __syncthreads();
  if (tid == 0) y[b] = fsig(red[32] + red[33] + bfv[0]);
}

// ---------- launch ----------
extern "C" void kernel_launch(void* const* d_in, const int* in_sizes, int n_in,
                              void* d_out, int out_size, void* d_ws, size_t ws_size,
                              hipStream_t stream){
  const float* x   = (const float*)d_in[0];
  const float* Wih = (const float*)d_in[1];
  const float* Whh = (const float*)d_in[2];
  const float* bih = (const float*)d_in[3];
  const float* bhh = (const float*)d_in[4];
  const float* Wa  = (const float*)d_in[5];
  const float* ba  = (const float*)d_in[6];
  const float* Wf  = (const float*)d_in[7];
  const float* bfv = (const float*)d_in[8];
  float* y = (float*)d_out;

  char* ws = (char*)d_ws;
  size_t off = 0;
  auto alloc = [&](size_t bytes) -> void* {
    void* p = ws + off; off += (bytes + 255) & ~(size_t)255; return p;
  };
  _Float16* xcvt  = (_Float16*)alloc((size_t)M_*H_*2);       // 33.5 MB
  _Float16* buf0  = (_Float16*)alloc((size_t)M_*H_*2);       // 33.5 MB
  _Float16* buf1  = (_Float16*)alloc((size_t)M_*H_*2);       // 33.5 MB
  _Float16* Wc    = (_Float16*)alloc((size_t)L_*512*256*2);  // 1.8 MB
  float*    biasc = (float*)   alloc((size_t)L_*512*4);      // 14 KB
  int*      flags = (int*)     alloc((size_t)L_*8*NCH*4);    // 28 KB

  hipMemsetAsync(flags, 0, (size_t)L_*8*NCH*4, stream);
  k_cvt_x<<<2048, 256, 0, stream>>>((const float4*)x, (f16x4*)xcvt, M_*F_/4);
  k_cvt_w<<<3584, 256, 0, stream>>>(Wih, Whh, bih, bhh, Wc, biasc);
  k_wave<<<56, 512, 0, stream>>>(xcvt, buf0, buf1, Wc, (const float4*)biasc, flags);
  k_attn<<<128, 256, 0, stream>>>(buf0, Wa, ba, Wf, bfv, y);
}